// Round 1
// baseline (34855.099 us; speedup 1.0000x reference)
//
#include <hip/hip_runtime.h>
#include <hip/hip_bf16.h>
#include <cstdint>
#include <cstddef>

#define T_STEPS 16384
#define HID 512
#define NWG 32          // scan workgroups; each owns 512/NWG = 16 hidden elems (48 w_hh rows)

// ---------------------------------------------------------------------------
// 64-lane sum via DPP (VALU pipe; avoids LDS-pipe ds_swizzle). Result in lane 63.
// Standard GCN row_shr/row_bcast chain, bound_ctrl=true (invalid lanes -> 0).
// ---------------------------------------------------------------------------
__device__ __forceinline__ float wave_reduce_sum(float x) {
#define DPP_ADD(ctrl)                                                          \
  x += __int_as_float(__builtin_amdgcn_update_dpp(                             \
      0, __float_as_int(x), (ctrl), 0xF, 0xF, true))
  DPP_ADD(0x111);  // row_shr:1
  DPP_ADD(0x112);  // row_shr:2
  DPP_ADD(0x114);  // row_shr:4
  DPP_ADD(0x118);  // row_shr:8  -> lane15 of each row16 holds row sum
  DPP_ADD(0x142);  // row_bcast:15 -> lane31 = R0+R1, lane63 = R2+R3
  DPP_ADD(0x143);  // row_bcast:31 -> lane63 = total
#undef DPP_ADD
  return x;
}

// ---------------------------------------------------------------------------
// Prep: fill hsz[0][:] = 0 (h0), hsz[1..T][:] = sentinel 2.0f (|h| < 1 always,
// so 2.0 is unreachable -> value-based sync token). Also bc = w_ih@enc_b + b_ih.
// Runs every launch (workspace is poisoned before timing; flags must be rebuilt).
// ---------------------------------------------------------------------------
__global__ void k_prep(float* __restrict__ hsz, float* __restrict__ bc,
                       const float* __restrict__ w_ih,
                       const float* __restrict__ enc_b,
                       const float* __restrict__ b_ih) {
  const int gid = blockIdx.x * blockDim.x + threadIdx.x;
  const int gsz = gridDim.x * blockDim.x;
  float4* h4 = reinterpret_cast<float4*>(hsz);
  const float4 zer = make_float4(0.f, 0.f, 0.f, 0.f);
  const float4 sen = make_float4(2.f, 2.f, 2.f, 2.f);
  const int n4 = (T_STEPS + 1) * HID / 4;
  for (int i = gid; i < n4; i += gsz) h4[i] = (i < HID / 4) ? zer : sen;
  if (gid < 3 * HID) {
    float acc = b_ih[gid];
    const float* wr = w_ih + (size_t)gid * HID;
    for (int j = 0; j < HID; ++j) acc = fmaf(wr[j], enc_b[j], acc);
    bc[gid] = acc;
  }
}

// ---------------------------------------------------------------------------
// 512x512 f32 transpose (enc_w -> enc_w^T) so the combined-weight GEMM can use
// the B^T (B[N,K]) form.
// ---------------------------------------------------------------------------
__global__ void k_transpose512(const float* __restrict__ in, float* __restrict__ out) {
  __shared__ float tile[32][33];
  const int bx = blockIdx.x * 32, by = blockIdx.y * 32;
  const int x = threadIdx.x, y = threadIdx.y;  // block (32,8)
#pragma unroll
  for (int i = 0; i < 32; i += 8) tile[y + i][x] = in[(size_t)(by + y + i) * 512 + bx + x];
  __syncthreads();
#pragma unroll
  for (int i = 0; i < 32; i += 8) out[(size_t)(bx + y + i) * 512 + by + x] = tile[x][y + i];
}

// ---------------------------------------------------------------------------
// f32 GEMM, C[M,N] = A[M,K] @ B[N,K]^T (+ bias[n]); out f32 or bf16.
// BM=BN=64, BK=16, 256 threads, 4x4 micro-tile. Correctness-first; ~50-70 TF.
// M,N multiples of 64; K multiple of 16 (all true here).
// ---------------------------------------------------------------------------
template <bool ADD_BIAS, bool OUT_BF16>
__global__ __launch_bounds__(256) void k_gemm_bt(
    const float* __restrict__ A, const float* __restrict__ B,
    const float* __restrict__ bias, void* __restrict__ C,
    int M, int N, int K) {
  __shared__ float As[16][68];  // [k][m], row stride 68 floats (16B-aligned, bank-skewed)
  __shared__ float Bs[16][68];  // [k][n]
  const int n0 = blockIdx.x * 64;
  const int m0 = blockIdx.y * 64;
  const int tid = (int)threadIdx.x;
  const int tx = tid & 15, ty = tid >> 4;
  const int lr = tid >> 2;          // 0..63  (tile row for loads)
  const int lc = (tid & 3) * 4;     // 0,4,8,12 (k offset for loads)

  float acc[4][4] = {};
  for (int k0 = 0; k0 < K; k0 += 16) {
    const float4 a4 = *reinterpret_cast<const float4*>(A + (size_t)(m0 + lr) * K + k0 + lc);
    const float4 b4 = *reinterpret_cast<const float4*>(B + (size_t)(n0 + lr) * K + k0 + lc);
    __syncthreads();  // previous compute done before overwrite
    As[lc + 0][lr] = a4.x; As[lc + 1][lr] = a4.y; As[lc + 2][lr] = a4.z; As[lc + 3][lr] = a4.w;
    Bs[lc + 0][lr] = b4.x; Bs[lc + 1][lr] = b4.y; Bs[lc + 2][lr] = b4.z; Bs[lc + 3][lr] = b4.w;
    __syncthreads();
#pragma unroll
    for (int kk = 0; kk < 16; ++kk) {
      const float4 av = *reinterpret_cast<const float4*>(&As[kk][ty * 4]);
      const float4 bv = *reinterpret_cast<const float4*>(&Bs[kk][tx * 4]);
      const float a[4] = {av.x, av.y, av.z, av.w};
      const float b[4] = {bv.x, bv.y, bv.z, bv.w};
#pragma unroll
      for (int i = 0; i < 4; ++i)
#pragma unroll
        for (int j = 0; j < 4; ++j) acc[i][j] = fmaf(a[i], b[j], acc[i][j]);
    }
  }

  float bv[4] = {0.f, 0.f, 0.f, 0.f};
  if (ADD_BIAS) {
#pragma unroll
    for (int j = 0; j < 4; ++j) bv[j] = bias[n0 + tx * 4 + j];
  }
#pragma unroll
  for (int i = 0; i < 4; ++i) {
    const int m = m0 + ty * 4 + i;
    if (OUT_BF16) {
      __hip_bfloat16* Cb = (__hip_bfloat16*)C;
#pragma unroll
      for (int j = 0; j < 4; ++j)
        Cb[(size_t)m * N + n0 + tx * 4 + j] = __float2bfloat16(acc[i][j] + bv[j]);
    } else {
      float4 v;
      v.x = acc[i][0] + bv[0]; v.y = acc[i][1] + bv[1];
      v.z = acc[i][2] + bv[2]; v.w = acc[i][3] + bv[3];
      *reinterpret_cast<float4*>((float*)C + (size_t)m * N + n0 + tx * 4) = v;
    }
  }
}

// ---------------------------------------------------------------------------
// Persistent GRU scan. 32 WGs x 512 threads, all co-resident (32 <= 256 CUs).
// WG b owns hidden elems [16b, 16b+16): w_hh rows {e, 512+e, 1024+e}.
// Wave w (of 8) handles local rows 6w..6w+5; lane = k mod 64; per-thread
// weights (48 f32) live in VGPRs for the whole sequence.
// Sync: value-based. hsz[t] pre-filled with 2.0f sentinel; |h|<1 strictly
// (h is a convex combination of tanh outputs starting from 0), so readers
// poll with relaxed AGENT-scope atomic loads (sc1 -> coherent point; safe
// across non-coherent per-XCD L2s) until all their 8 values are < 1.5f.
// Writers publish with relaxed AGENT atomic stores. No fences needed.
// ---------------------------------------------------------------------------
__global__ __launch_bounds__(512) void k_scan(
    const float* __restrict__ w_hh,           // [1536][512] f32
    const __hip_bfloat16* __restrict__ igb,   // [T][1536] bf16 (ir|iz|in)
    const float* __restrict__ b_n,            // [512]
    float* __restrict__ hsz)                  // [T+1][512] f32; [0]=0, rest sentinel
{
  const int b = blockIdx.x;
  const int tid = (int)threadIdx.x;
  const int wave = tid >> 6;
  const int lane = tid & 63;
  const int E0 = b * 16;

  // preload weights into registers: wreg[i][j] = w_hh[grow(6*wave+i)][lane + 64*j]
  float wreg[6][8];
#pragma unroll
  for (int i = 0; i < 6; ++i) {
    const int lr = 6 * wave + i;
    const int gr = (lr < 16) ? (E0 + lr)
                 : (lr < 32) ? (512 + E0 + (lr - 16))
                             : (1024 + E0 + (lr - 32));
    const float* wrow = w_hh + (size_t)gr * HID;
#pragma unroll
    for (int j = 0; j < 8; ++j) wreg[i][j] = wrow[lane + 64 * j];
  }

  float bn_e = 0.f, h_e = 0.f;  // per-owned-elem state for threads 0..15
  if (tid < 16) bn_e = b_n[E0 + tid];

  __shared__ float g_lds[48];  // local row sums: [0..15]=hr, [16..31]=hz, [32..47]=hn

#pragma unroll 1
  for (int t = 0; t < T_STEPS; ++t) {
    float hv[8];
    if (t > 0) {
      float* hrow = hsz + (size_t)t * HID;
      while (true) {
        bool ok = true;
#pragma unroll
        for (int j = 0; j < 8; ++j) {
          hv[j] = __hip_atomic_load(&hrow[lane + 64 * j], __ATOMIC_RELAXED,
                                    __HIP_MEMORY_SCOPE_AGENT);
          ok &= (hv[j] < 1.5f);
        }
        if (__all(ok)) break;
      }
    } else {
#pragma unroll
      for (int j = 0; j < 8; ++j) hv[j] = 0.f;
    }

    // 6 row-dots + wave reduction
#pragma unroll
    for (int i = 0; i < 6; ++i) {
      float s = 0.f;
#pragma unroll
      for (int j = 0; j < 8; ++j) s = fmaf(wreg[i][j], hv[j], s);
      s = wave_reduce_sum(s);
      if (lane == 63) g_lds[6 * wave + i] = s;
    }
    __syncthreads();

    // gate combine on threads 0..15 (one per owned elem)
    if (tid < 16) {
      const int e = tid;
      const float hr = g_lds[e], hz = g_lds[16 + e], hn = g_lds[32 + e];
      const __hip_bfloat16* igrow = igb + (size_t)t * (3 * HID);
      const float ir  = __bfloat162float(igrow[E0 + e]);
      const float iz  = __bfloat162float(igrow[512 + E0 + e]);
      const float inn = __bfloat162float(igrow[1024 + E0 + e]);
      const float r = 1.f / (1.f + __expf(-(ir + hr)));
      const float z = 1.f / (1.f + __expf(-(iz + hz)));
      const float n = tanhf(inn + r * (hn + bn_e));
      const float hnew = n + z * (h_e - n);
      h_e = hnew;
      __hip_atomic_store(&hsz[(size_t)(t + 1) * HID + E0 + e], hnew,
                         __ATOMIC_RELAXED, __HIP_MEMORY_SCOPE_AGENT);
    }
    __syncthreads();  // g_lds reuse barrier for next step
  }
}

// ---------------------------------------------------------------------------
extern "C" void kernel_launch(void* const* d_in, const int* in_sizes, int n_in,
                              void* d_out, int out_size, void* d_ws, size_t ws_size,
                              hipStream_t stream) {
  (void)in_sizes; (void)n_in; (void)out_size; (void)ws_size;
  const float* x     = (const float*)d_in[0];  // [T,512]
  const float* enc_w = (const float*)d_in[1];  // [512,512]
  const float* enc_b = (const float*)d_in[2];  // [512]
  const float* w_ih  = (const float*)d_in[3];  // [1536,512]
  const float* w_hh  = (const float*)d_in[4];  // [1536,512]
  const float* b_ih  = (const float*)d_in[5];  // [1536]
  const float* b_n   = (const float*)d_in[6];  // [512]
  const float* dec_w = (const float*)d_in[7];  // [512,512]
  const float* dec_b = (const float*)d_in[8];  // [512]
  float* out = (float*)d_out;                  // [T,512] f32

  // workspace carve-out (256B aligned): ~88 MB total
  uintptr_t p = (uintptr_t)d_ws;
  auto carve = [&](size_t bytes) {
    void* r = (void*)p;
    p += (bytes + 255) & ~(size_t)255;
    return r;
  };
  float* encwT          = (float*)carve((size_t)512 * 512 * 4);            // enc_w^T
  float* Wc             = (float*)carve((size_t)1536 * 512 * 4);           // w_ih@enc_w
  float* bc             = (float*)carve((size_t)1536 * 4);                 // w_ih@enc_b + b_ih
  __hip_bfloat16* igb   = (__hip_bfloat16*)carve((size_t)T_STEPS * 1536 * 2);
  float* hsz            = (float*)carve((size_t)(T_STEPS + 1) * HID * 4);  // h_0..h_T

  // 1. sentinel fill + bc
  k_prep<<<1024, 256, 0, stream>>>(hsz, bc, w_ih, enc_b, b_ih);
  // 2. enc_w transpose
  k_transpose512<<<dim3(16, 16), dim3(32, 8), 0, stream>>>(enc_w, encwT);
  // 3. Wc = w_ih @ enc_w   (M=1536, N=512, K=512)
  k_gemm_bt<false, false><<<dim3(512 / 64, 1536 / 64), 256, 0, stream>>>(
      w_ih, encwT, nullptr, Wc, 1536, 512, 512);
  // 4. igates = x @ Wc^T + bc  (M=16384, N=1536, K=512) -> bf16
  k_gemm_bt<true, true><<<dim3(1536 / 64, 16384 / 64), 256, 0, stream>>>(
      x, Wc, bc, igb, T_STEPS, 1536, 512);
  // 5. the serial GRU scan
  k_scan<<<NWG, 512, 0, stream>>>(w_hh, igb, b_n, hsz);
  // 6. preds = hs @ dec_w^T + dec_b  (M=16384, N=512, K=512) -> f32 out
  k_gemm_bt<true, false><<<dim3(512 / 64, 16384 / 64), 256, 0, stream>>>(
      hsz + HID, dec_w, dec_b, out, T_STEPS, 512, 512);
}

// Round 2
// 34042.798 us; speedup vs baseline: 1.0239x; 1.0239x over previous
//
#include <hip/hip_runtime.h>
#include <hip/hip_bf16.h>
#include <cstdint>
#include <cstddef>

#define T_STEPS 16384
#define HID 512
#define NWG 32          // 32 WGs x 512 thr = 256 waves; wave w owns elems {2w, 2w+1}

// ---------------------------------------------------------------------------
// 64-lane sum via DPP (VALU pipe). Result valid in lane 63.
// ---------------------------------------------------------------------------
__device__ __forceinline__ float wave_reduce_sum(float x) {
#define DPP_ADD(ctrl)                                                          \
  x += __int_as_float(__builtin_amdgcn_update_dpp(                             \
      0, __float_as_int(x), (ctrl), 0xF, 0xF, true))
  DPP_ADD(0x111);  // row_shr:1
  DPP_ADD(0x112);  // row_shr:2
  DPP_ADD(0x114);  // row_shr:4
  DPP_ADD(0x118);  // row_shr:8
  DPP_ADD(0x142);  // row_bcast:15
  DPP_ADD(0x143);  // row_bcast:31 -> lane63 = total
#undef DPP_ADD
  return x;
}

__device__ __forceinline__ float fsigmoid(float x) {
  return __builtin_amdgcn_rcpf(1.f + __expf(-x));
}
__device__ __forceinline__ float ftanh(float x) {
  // 1 - 2/(1+e^{2x}); saturates correctly via exp->inf->rcp->0
  return 1.f - 2.f * __builtin_amdgcn_rcpf(1.f + __expf(2.f * x));
}

// ---------------------------------------------------------------------------
// Prep: hsz[0][:]=0 (h0), hsz[1..T][:]=sentinel 2.0f (|h|<1 strictly, so 2.0
// is an unreachable value-sync token). bc = w_ih@enc_b + b_ih.
// Re-runs every launch (graph replays leave hsz full of valid h values).
// ---------------------------------------------------------------------------
__global__ void k_prep(float* __restrict__ hsz, float* __restrict__ bc,
                       const float* __restrict__ w_ih,
                       const float* __restrict__ enc_b,
                       const float* __restrict__ b_ih) {
  const int gid = blockIdx.x * blockDim.x + threadIdx.x;
  const int gsz = gridDim.x * blockDim.x;
  float4* h4 = reinterpret_cast<float4*>(hsz);
  const float4 zer = make_float4(0.f, 0.f, 0.f, 0.f);
  const float4 sen = make_float4(2.f, 2.f, 2.f, 2.f);
  const int n4 = (T_STEPS + 1) * HID / 4;
  for (int i = gid; i < n4; i += gsz) h4[i] = (i < HID / 4) ? zer : sen;
  if (gid < 3 * HID) {
    float acc = b_ih[gid];
    const float* wr = w_ih + (size_t)gid * HID;
    for (int j = 0; j < HID; ++j) acc = fmaf(wr[j], enc_b[j], acc);
    bc[gid] = acc;
  }
}

// ---------------------------------------------------------------------------
// 512x512 f32 transpose (enc_w -> enc_w^T).
// ---------------------------------------------------------------------------
__global__ void k_transpose512(const float* __restrict__ in, float* __restrict__ out) {
  __shared__ float tile[32][33];
  const int bx = blockIdx.x * 32, by = blockIdx.y * 32;
  const int x = threadIdx.x, y = threadIdx.y;  // block (32,8)
#pragma unroll
  for (int i = 0; i < 32; i += 8) tile[y + i][x] = in[(size_t)(by + y + i) * 512 + bx + x];
  __syncthreads();
#pragma unroll
  for (int i = 0; i < 32; i += 8) out[(size_t)(bx + y + i) * 512 + by + x] = tile[x][y + i];
}

// ---------------------------------------------------------------------------
// f32 GEMM, C[M,N] = A[M,K] @ B[N,K]^T (+ bias[n]); out f32 or bf16.
// ---------------------------------------------------------------------------
template <bool ADD_BIAS, bool OUT_BF16>
__global__ __launch_bounds__(256) void k_gemm_bt(
    const float* __restrict__ A, const float* __restrict__ B,
    const float* __restrict__ bias, void* __restrict__ C,
    int M, int N, int K) {
  __shared__ float As[16][68];
  __shared__ float Bs[16][68];
  const int n0 = blockIdx.x * 64;
  const int m0 = blockIdx.y * 64;
  const int tid = (int)threadIdx.x;
  const int tx = tid & 15, ty = tid >> 4;
  const int lr = tid >> 2;
  const int lc = (tid & 3) * 4;

  float acc[4][4] = {};
  for (int k0 = 0; k0 < K; k0 += 16) {
    const float4 a4 = *reinterpret_cast<const float4*>(A + (size_t)(m0 + lr) * K + k0 + lc);
    const float4 b4 = *reinterpret_cast<const float4*>(B + (size_t)(n0 + lr) * K + k0 + lc);
    __syncthreads();
    As[lc + 0][lr] = a4.x; As[lc + 1][lr] = a4.y; As[lc + 2][lr] = a4.z; As[lc + 3][lr] = a4.w;
    Bs[lc + 0][lr] = b4.x; Bs[lc + 1][lr] = b4.y; Bs[lc + 2][lr] = b4.z; Bs[lc + 3][lr] = b4.w;
    __syncthreads();
#pragma unroll
    for (int kk = 0; kk < 16; ++kk) {
      const float4 av = *reinterpret_cast<const float4*>(&As[kk][ty * 4]);
      const float4 bv = *reinterpret_cast<const float4*>(&Bs[kk][tx * 4]);
      const float a[4] = {av.x, av.y, av.z, av.w};
      const float b[4] = {bv.x, bv.y, bv.z, bv.w};
#pragma unroll
      for (int i = 0; i < 4; ++i)
#pragma unroll
        for (int j = 0; j < 4; ++j) acc[i][j] = fmaf(a[i], b[j], acc[i][j]);
    }
  }

  float bv[4] = {0.f, 0.f, 0.f, 0.f};
  if (ADD_BIAS) {
#pragma unroll
    for (int j = 0; j < 4; ++j) bv[j] = bias[n0 + tx * 4 + j];
  }
#pragma unroll
  for (int i = 0; i < 4; ++i) {
    const int m = m0 + ty * 4 + i;
    if (OUT_BF16) {
      __hip_bfloat16* Cb = (__hip_bfloat16*)C;
#pragma unroll
      for (int j = 0; j < 4; ++j)
        Cb[(size_t)m * N + n0 + tx * 4 + j] = __float2bfloat16(acc[i][j] + bv[j]);
    } else {
      float4 v;
      v.x = acc[i][0] + bv[0]; v.y = acc[i][1] + bv[1];
      v.z = acc[i][2] + bv[2]; v.w = acc[i][3] + bv[3];
      *reinterpret_cast<float4*>((float*)C + (size_t)m * N + n0 + tx * 4) = v;
    }
  }
}

// ---------------------------------------------------------------------------
// Persistent GRU scan, wave-decoupled. 256 waves; wave w owns hidden elems
// {2w, 2w+1} = w_hh rows {e, 512+e, 1024+e} for each e. Per-thread weights
// (48 f32) pinned in VGPRs. NO barriers / LDS in the 16384-step loop.
// Per step: issue ig loads (independent of h) -> poll h_t sentinel ->
// 6 row-dots + DPP reduce -> lane63 computes both elems' gates -> 2 stores.
// Sync is value-based: hsz pre-filled with 2.0f; |h|<1 strictly; readers use
// relaxed agent-scope atomic loads (coherent point; safe across XCD L2s).
// ---------------------------------------------------------------------------
__global__ __launch_bounds__(512) void k_scan(
    const float* __restrict__ w_hh,           // [1536][512] f32
    const __hip_bfloat16* __restrict__ igb,   // [T][1536] bf16 (ir|iz|in)
    const float* __restrict__ b_n,            // [512]
    float* __restrict__ hsz)                  // [T+1][512] f32
{
  const int wid = blockIdx.x * (512 / 64) + ((int)threadIdx.x >> 6);  // 0..255
  const int lane = (int)threadIdx.x & 63;
  const int e0 = wid * 2;  // owns e0, e0+1

  // wreg[i][j] = w_hh[512*(i>>1) + e0 + (i&1)][lane + 64*j], pinned in VGPRs
  float wreg[6][8];
#pragma unroll
  for (int i = 0; i < 6; ++i) {
    const float* wrow = w_hh + (size_t)((i >> 1) * HID + e0 + (i & 1)) * HID;
#pragma unroll
    for (int j = 0; j < 8; ++j) {
      wreg[i][j] = wrow[lane + 64 * j];
      asm volatile("" : "+v"(wreg[i][j]));  // force materialization pre-loop
    }
  }

  float bn0 = 0.f, bn1 = 0.f, h0 = 0.f, h1 = 0.f;
  if (lane == 63) { bn0 = b_n[e0]; bn1 = b_n[e0 + 1]; }

  const uint32_t* ig32base = reinterpret_cast<const uint32_t*>(igb);

#pragma unroll 1
  for (int t = 0; t < T_STEPS; ++t) {
    // --- prefetch ig triples for both elems (3 x u32 = 6 bf16), lane 63 only.
    // Issued BEFORE the poll; HBM latency hides under the sync wait.
    uint32_t g_r = 0, g_z = 0, g_n = 0;
    if (lane == 63) {
      const uint32_t* igrow = ig32base + (size_t)t * 768;  // 1536 bf16 = 768 u32
      g_r = igrow[(e0 >> 1)];
      g_z = igrow[256 + (e0 >> 1)];
      g_n = igrow[512 + (e0 >> 1)];
    }

    // --- poll h_t (value-based sentinel sync)
    float hv[8];
    if (t > 0) {
      const float* hrow = hsz + (size_t)t * HID;
      bool ok;
      do {
        ok = true;
#pragma unroll
        for (int j = 0; j < 8; ++j) {
          hv[j] = __hip_atomic_load(&hrow[lane + 64 * j], __ATOMIC_RELAXED,
                                    __HIP_MEMORY_SCOPE_AGENT);
          ok &= (hv[j] < 1.5f);
        }
      } while (!__all(ok));
    } else {
#pragma unroll
      for (int j = 0; j < 8; ++j) hv[j] = 0.f;
    }

    // --- 6 row-dots, DPP-reduced into lane 63
    float s[6];
#pragma unroll
    for (int i = 0; i < 6; ++i) {
      float acc = 0.f;
#pragma unroll
      for (int j = 0; j < 8; ++j) acc = fmaf(wreg[i][j], hv[j], acc);
      s[i] = wave_reduce_sum(acc);
    }

    // --- gates + state update + publish (lane 63; both owned elems)
    if (lane == 63) {
      // bf16 pair -> two f32 (low half = e0, high half = e0+1)
      const float ir0 = __uint_as_float(g_r << 16);
      const float ir1 = __uint_as_float(g_r & 0xffff0000u);
      const float iz0 = __uint_as_float(g_z << 16);
      const float iz1 = __uint_as_float(g_z & 0xffff0000u);
      const float in0 = __uint_as_float(g_n << 16);
      const float in1 = __uint_as_float(g_n & 0xffff0000u);

      const float r0 = fsigmoid(ir0 + s[0]);
      const float r1 = fsigmoid(ir1 + s[1]);
      const float z0 = fsigmoid(iz0 + s[2]);
      const float z1 = fsigmoid(iz1 + s[3]);
      const float n0 = ftanh(in0 + r0 * (s[4] + bn0));
      const float n1 = ftanh(in1 + r1 * (s[5] + bn1));
      h0 = n0 + z0 * (h0 - n0);
      h1 = n1 + z1 * (h1 - n1);

      float* dst = hsz + (size_t)(t + 1) * HID + e0;
      __hip_atomic_store(dst + 0, h0, __ATOMIC_RELAXED, __HIP_MEMORY_SCOPE_AGENT);
      __hip_atomic_store(dst + 1, h1, __ATOMIC_RELAXED, __HIP_MEMORY_SCOPE_AGENT);
    }
  }
}

// ---------------------------------------------------------------------------
extern "C" void kernel_launch(void* const* d_in, const int* in_sizes, int n_in,
                              void* d_out, int out_size, void* d_ws, size_t ws_size,
                              hipStream_t stream) {
  (void)in_sizes; (void)n_in; (void)out_size; (void)ws_size;
  const float* x     = (const float*)d_in[0];  // [T,512]
  const float* enc_w = (const float*)d_in[1];  // [512,512]
  const float* enc_b = (const float*)d_in[2];  // [512]
  const float* w_ih  = (const float*)d_in[3];  // [1536,512]
  const float* w_hh  = (const float*)d_in[4];  // [1536,512]
  const float* b_ih  = (const float*)d_in[5];  // [1536]
  const float* b_n   = (const float*)d_in[6];  // [512]
  const float* dec_w = (const float*)d_in[7];  // [512,512]
  const float* dec_b = (const float*)d_in[8];  // [512]
  float* out = (float*)d_out;                  // [T,512] f32

  uintptr_t p = (uintptr_t)d_ws;
  auto carve = [&](size_t bytes) {
    void* r = (void*)p;
    p += (bytes + 255) & ~(size_t)255;
    return r;
  };
  float* encwT        = (float*)carve((size_t)512 * 512 * 4);
  float* Wc           = (float*)carve((size_t)1536 * 512 * 4);
  float* bc           = (float*)carve((size_t)1536 * 4);
  __hip_bfloat16* igb = (__hip_bfloat16*)carve((size_t)T_STEPS * 1536 * 2);
  float* hsz          = (float*)carve((size_t)(T_STEPS + 1) * HID * 4);

  k_prep<<<1024, 256, 0, stream>>>(hsz, bc, w_ih, enc_b, b_ih);
  k_transpose512<<<dim3(16, 16), dim3(32, 8), 0, stream>>>(enc_w, encwT);
  k_gemm_bt<false, false><<<dim3(512 / 64, 1536 / 64), 256, 0, stream>>>(
      w_ih, encwT, nullptr, Wc, 1536, 512, 512);
  k_gemm_bt<true, true><<<dim3(1536 / 64, 16384 / 64), 256, 0, stream>>>(
      x, Wc, bc, igb, T_STEPS, 1536, 512);
  k_scan<<<NWG, 512, 0, stream>>>(w_hh, igb, b_n, hsz);
  k_gemm_bt<true, false><<<dim3(512 / 64, 16384 / 64), 256, 0, stream>>>(
      hsz + HID, dec_w, dec_b, out, T_STEPS, 512, 512);
}